// Round 3
// baseline (194.231 us; speedup 1.0000x reference)
//
#include <hip/hip_runtime.h>

#define V_CNT 6890
#define N_B 512
#define NP 207          // (24-1)*9
#define KPAD 224        // 207 lrotmin + 10 beta + 7 zero
#define RTOT 20670      // V*3
#define RPAD 20736      // 108 * 192
#define PREP_BLKS 2268  // RPAD*KPAD/8/256
#define JS1_BLKS 384    // 16 chunks x 24 joints

typedef unsigned short ushort_t;
typedef __attribute__((ext_vector_type(4))) float f32x4;
typedef __attribute__((ext_vector_type(8))) short s16x8;
typedef __attribute__((ext_vector_type(4))) float f4a;

// ws layout (bytes)
#define O_PART 0u         // 24*16*33 f32 = 50688
#define O_G    65536u     // 512*288 f32 = 589824
#define O_A    655360u    // 512*224 bf16 = 229376
#define O_B    1048576u   // 20736*224 bf16 = 9.3MB

__device__ __constant__ int PAR[24] = {0,0,0,0,1,2,3,4,5,6,7,8,9,9,9,12,13,14,16,17,18,19,20,21};

__device__ __forceinline__ ushort_t f2bf(float f) {
    union { float f; unsigned u; } x; x.f = f;
    unsigned u = x.u + 0x7fffu + ((x.u >> 16) & 1u);
    return (ushort_t)(u >> 16);
}

// ---------- K1: B-matrix prep (blocks 0..2267) + JS/JT partials (blocks 2268..2651) ----------
__global__ __launch_bounds__(256) void k_pre(const float* __restrict__ pdirs,
                                             const float* __restrict__ sdirs,
                                             const float* __restrict__ vtemp,
                                             const float* __restrict__ jreg,
                                             ushort_t* __restrict__ Bm,
                                             float* __restrict__ part) {
    int b = blockIdx.x;
    int tid = threadIdx.x;
    if (b < PREP_BLKS) {
        int g = b * 256 + tid;           // 0 .. 580607
        int r = g / 28;                  // row 0..20735
        int k0 = (g - r * 28) * 8;       // 0,8,...,216
        s16x8 pk;
        if (r < RTOT) {
            const float* pr = pdirs + (size_t)r * NP;
            const float* sr = sdirs + (size_t)r * 10;
#pragma unroll
            for (int i = 0; i < 8; i++) {
                int k = k0 + i;
                float v = 0.f;
                if (k < NP) v = pr[k];
                else if (k < 217) v = sr[k - NP];
                pk[i] = (short)f2bf(v);
            }
        } else {
#pragma unroll
            for (int i = 0; i < 8; i++) pk[i] = 0;
        }
        *(s16x8*)(Bm + (size_t)r * KPAD + k0) = pk;
    } else {
        int b2 = b - PREP_BLKS;          // j*16 + ch
        int ch = b2 & 15;
        int j = b2 >> 4;
        int v0 = ch * 432;
        int vend = v0 + 432; if (vend > V_CNT) vend = V_CNT;
        float acc[33];
#pragma unroll
        for (int i = 0; i < 33; i++) acc[i] = 0.f;
        for (int v = v0 + tid; v < vend; v += 256) {
            float r = jreg[j * V_CNT + v];
            const float* sd = sdirs + v * 30;
#pragma unroll
            for (int i = 0; i < 30; i++) acc[i] += r * sd[i];
            acc[30] += r * vtemp[v * 3 + 0];
            acc[31] += r * vtemp[v * 3 + 1];
            acc[32] += r * vtemp[v * 3 + 2];
        }
        // wave reduction (64 lanes)
#pragma unroll
        for (int off = 32; off > 0; off >>= 1) {
#pragma unroll
            for (int i = 0; i < 33; i++) acc[i] += __shfl_down(acc[i], off);
        }
        __shared__ float red[4][33];
        int w = tid >> 6, lane = tid & 63;
        if (lane == 0) {
#pragma unroll
            for (int i = 0; i < 33; i++) red[w][i] = acc[i];
        }
        __syncthreads();
        if (tid < 33) {
            float s = red[0][tid] + red[1][tid] + red[2][tid] + red[3][tid];
            part[b2 * 33 + tid] = s;
        }
    }
}

// ---------- K2: js2 reduce + per-n chain (4 n / block) -> G'[n][24][12], A[n][224] bf16 ----------
__global__ __launch_bounds__(256) void k_chain(const float* __restrict__ beta,
                                               const float* __restrict__ pose,
                                               const float* __restrict__ part,
                                               float* __restrict__ ws_g,
                                               ushort_t* __restrict__ Am) {
    __shared__ float JSl[720];
    __shared__ float JTl[72];
    __shared__ float Rl[4][24][9];
    __shared__ float Jl[4][24][3];
    __shared__ float Tm[4][24][16];
    __shared__ float G[4][24][16];
    int tid = threadIdx.x;

    // fused js2: reduce 16 chunk-partials
    for (int t = tid; t < 792; t += 256) {
        int j = t / 33, i = t - j * 33;
        float s = 0.f;
#pragma unroll
        for (int c = 0; c < 16; c++) s += part[(j * 16 + c) * 33 + i];
        if (i < 30) JSl[j * 30 + i] = s;
        else        JTl[j * 3 + (i - 30)] = s;
    }
    __syncthreads();

    int sub = tid >> 6, lane = tid & 63;
    int n = blockIdx.x * 4 + sub;

    if (lane < 24) {
        int t = lane;
        float x = pose[n * 72 + t * 3 + 0];
        float y = pose[n * 72 + t * 3 + 1];
        float z = pose[n * 72 + t * 3 + 2];
        float th = sqrtf(x * x + y * y + z * z) + 1e-8f;
        float inv = 1.f / th;
        float rx = x * inv, ry = y * inv, rz = z * inv;
        float c = cosf(th), s = sinf(th), omc = 1.f - c;
        Rl[sub][t][0] = c + omc * rx * rx;
        Rl[sub][t][1] = omc * rx * ry - s * rz;
        Rl[sub][t][2] = omc * rx * rz + s * ry;
        Rl[sub][t][3] = omc * ry * rx + s * rz;
        Rl[sub][t][4] = c + omc * ry * ry;
        Rl[sub][t][5] = omc * ry * rz - s * rx;
        Rl[sub][t][6] = omc * rz * rx - s * ry;
        Rl[sub][t][7] = omc * rz * ry + s * rx;
        Rl[sub][t][8] = c + omc * rz * rz;
#pragma unroll
        for (int cc = 0; cc < 3; cc++) {
            float a = JTl[t * 3 + cc];
#pragma unroll
            for (int b = 0; b < 10; b++) a += beta[n * 10 + b] * JSl[(t * 3 + cc) * 10 + b];
            Jl[sub][t][cc] = a;
        }
    }
    __syncthreads();
    if (lane < 24) {
        int t = lane;
        int p = PAR[t];
        float tx, ty, tz;
        if (t == 0) { tx = Jl[sub][0][0]; ty = Jl[sub][0][1]; tz = Jl[sub][0][2]; }
        else { tx = Jl[sub][t][0] - Jl[sub][p][0]; ty = Jl[sub][t][1] - Jl[sub][p][1]; tz = Jl[sub][t][2] - Jl[sub][p][2]; }
        Tm[sub][t][0] = Rl[sub][t][0]; Tm[sub][t][1] = Rl[sub][t][1]; Tm[sub][t][2]  = Rl[sub][t][2]; Tm[sub][t][3]  = tx;
        Tm[sub][t][4] = Rl[sub][t][3]; Tm[sub][t][5] = Rl[sub][t][4]; Tm[sub][t][6]  = Rl[sub][t][5]; Tm[sub][t][7]  = ty;
        Tm[sub][t][8] = Rl[sub][t][6]; Tm[sub][t][9] = Rl[sub][t][7]; Tm[sub][t][10] = Rl[sub][t][8]; Tm[sub][t][11] = tz;
        Tm[sub][t][12] = 0.f; Tm[sub][t][13] = 0.f; Tm[sub][t][14] = 0.f; Tm[sub][t][15] = 1.f;
    }
    __syncthreads();
    if (lane < 16) G[sub][0][lane] = Tm[sub][0][lane];
    __syncthreads();
    for (int i = 1; i < 24; i++) {
        int p = PAR[i];
        if (lane < 16) {
            int a = lane >> 2, bb = lane & 3;
            float s = G[sub][p][a * 4 + 0] * Tm[sub][i][0 * 4 + bb]
                    + G[sub][p][a * 4 + 1] * Tm[sub][i][1 * 4 + bb]
                    + G[sub][p][a * 4 + 2] * Tm[sub][i][2 * 4 + bb]
                    + G[sub][p][a * 4 + 3] * Tm[sub][i][3 * 4 + bb];
            G[sub][i][lane] = s;
        }
        __syncthreads();
    }
    if (lane < 24) {
        int t = lane;
        float jx = Jl[sub][t][0], jy = Jl[sub][t][1], jz = Jl[sub][t][2];
        float* outp = ws_g + (n * 24 + t) * 12;
#pragma unroll
        for (int a = 0; a < 3; a++) {
            float g0 = G[sub][t][a * 4 + 0], g1 = G[sub][t][a * 4 + 1];
            float g2 = G[sub][t][a * 4 + 2], g3 = G[sub][t][a * 4 + 3];
            outp[a * 4 + 0] = g0;
            outp[a * 4 + 1] = g1;
            outp[a * 4 + 2] = g2;
            outp[a * 4 + 3] = g3 - (g0 * jx + g1 * jy + g2 * jz);
        }
    }
    // A row: [lrotmin(207) | beta(10) | 0(7)] bf16
    for (int idx = lane; idx < KPAD; idx += 64) {
        float val;
        if (idx < NP) {
            int j = 1 + idx / 9;
            int e = idx - (j - 1) * 9;
            float d = (e == 0 || e == 4 || e == 8) ? 1.f : 0.f;
            val = Rl[sub][j][e] - d;
        } else if (idx < 217) {
            val = beta[n * 10 + (idx - NP)];
        } else val = 0.f;
        Am[n * KPAD + idx] = f2bf(val);
    }
}

// ---------- K3: MFMA GEMM (64n x 192r) + fused LBS epilogue ----------
// grid (108 v-tiles of 64, 8 n-tiles of 64), 256 thr / 4 waves, wave tile 32n x 96r
__global__ __launch_bounds__(256) void k_gl(const ushort_t* __restrict__ A,
                                            const ushort_t* __restrict__ B,
                                            const float* __restrict__ vtemp,
                                            const float* __restrict__ wts,
                                            const float* __restrict__ ws_g,
                                            float* __restrict__ out) {
    __shared__ float smem[64 * 194];              // 49664 B; staging aliased below
    ushort_t* a_lds = (ushort_t*)smem;            // 64*40
    ushort_t* b_lds = (ushort_t*)smem + 64 * 40;  // 192*40
    int tid = threadIdx.x;
    int v0 = blockIdx.x * 64;
    int n0 = blockIdx.y * 64;
    int w = tid >> 6, lane = tid & 63;
    int quad = lane >> 4, lm = lane & 15;
    int m0w = (w >> 1) * 32, r0w = (w & 1) * 96;

    f32x4 acc[2][6];
#pragma unroll
    for (int a = 0; a < 2; a++)
#pragma unroll
        for (int b = 0; b < 6; b++) acc[a][b] = (f32x4)0.f;

    int srow = tid >> 2, koff = (tid & 3) * 8;
    const ushort_t* ag = A + (n0 + srow) * KPAD + koff;
    const ushort_t* bg = B + (size_t)(v0 * 3 + srow) * KPAD + koff;

#pragma unroll 1
    for (int kc = 0; kc < 7; kc++) {
        s16x8 av  = *(const s16x8*)(ag + kc * 32);
        s16x8 bv0 = *(const s16x8*)(bg + kc * 32);
        s16x8 bv1 = *(const s16x8*)(bg + 64 * KPAD + kc * 32);
        s16x8 bv2 = *(const s16x8*)(bg + 128 * KPAD + kc * 32);
        __syncthreads();
        *(s16x8*)&a_lds[srow * 40 + koff] = av;
        *(s16x8*)&b_lds[srow * 40 + koff] = bv0;
        *(s16x8*)&b_lds[(srow + 64) * 40 + koff] = bv1;
        *(s16x8*)&b_lds[(srow + 128) * 40 + koff] = bv2;
        __syncthreads();
        s16x8 af[2], bf[6];
#pragma unroll
        for (int mt = 0; mt < 2; mt++)
            af[mt] = *(const s16x8*)&a_lds[(m0w + mt * 16 + lm) * 40 + quad * 8];
#pragma unroll
        for (int rt = 0; rt < 6; rt++)
            bf[rt] = *(const s16x8*)&b_lds[(r0w + rt * 16 + lm) * 40 + quad * 8];
#pragma unroll
        for (int mt = 0; mt < 2; mt++)
#pragma unroll
            for (int rt = 0; rt < 6; rt++)
                acc[mt][rt] = __builtin_amdgcn_mfma_f32_16x16x32_bf16(af[mt], bf[rt], acc[mt][rt], 0, 0, 0);
    }

    // load per-vertex weights while waiting (regs), vertex = lane
    int v = v0 + lane;
    int ve = v < V_CNT ? v : V_CNT - 1;
    float wreg[24];
    {
        const f4a* wr = (const f4a*)(wts + ve * 24);
#pragma unroll
        for (int q = 0; q < 6; q++) {
            f4a t = wr[q];
#pragma unroll
            for (int u = 0; u < 4; u++) wreg[q * 4 + u] = t[u];
        }
    }
    float vt0 = vtemp[ve * 3 + 0], vt1 = vtemp[ve * 3 + 1], vt2 = vtemp[ve * 3 + 2];

    __syncthreads();  // staging LDS no longer needed
    // write pb tile: row = n_local, col = r_local, stride 194 (2-way bank alias only)
#pragma unroll
    for (int mt = 0; mt < 2; mt++) {
#pragma unroll
        for (int rt = 0; rt < 6; rt++) {
            int row = m0w + mt * 16 + quad * 4;
            int col = r0w + rt * 16 + lm;
#pragma unroll
            for (int i = 0; i < 4; i++)
                smem[(row + i) * 194 + col] = acc[mt][rt][i];
        }
    }
    __syncthreads();

    // LBS: wave w handles n_local = w*16..w*16+15, all 64 vertices (lane = v_local)
    int wu = __builtin_amdgcn_readfirstlane(w);
    const float* gbase = ws_g + (size_t)(n0 + wu * 16) * 288;
#pragma unroll 1
    for (int ni = 0; ni < 16; ni++) {
        const float* g = gbase + ni * 288;
        float T[12];
#pragma unroll
        for (int q = 0; q < 12; q++) T[q] = 0.f;
#pragma unroll
        for (int j = 0; j < 24; j++) {
            float wj = wreg[j];
#pragma unroll
            for (int q = 0; q < 12; q++) T[q] += wj * g[j * 12 + q];
        }
        int nrow = wu * 16 + ni;
        float px = smem[nrow * 194 + 3 * lane + 0] + vt0;
        float py = smem[nrow * 194 + 3 * lane + 1] + vt1;
        float pz = smem[nrow * 194 + 3 * lane + 2] + vt2;
        float o0 = T[3]  + T[0] * px + T[1] * py + T[2]  * pz;
        float o1 = T[7]  + T[4] * px + T[5] * py + T[6]  * pz;
        float o2 = T[11] + T[8] * px + T[9] * py + T[10] * pz;
        if (v < V_CNT) {
            float* op = out + ((size_t)(n0 + nrow) * V_CNT + v) * 3;
            op[0] = o0; op[1] = o1; op[2] = o2;
        }
    }
}

extern "C" void kernel_launch(void* const* d_in, const int* in_sizes, int n_in,
                              void* d_out, int out_size, void* d_ws, size_t ws_size,
                              hipStream_t stream) {
    const float* beta  = (const float*)d_in[0];
    const float* pose  = (const float*)d_in[1];
    const float* vtemp = (const float*)d_in[2];
    const float* sdirs = (const float*)d_in[3];
    const float* pdirs = (const float*)d_in[4];
    const float* jreg  = (const float*)d_in[5];
    const float* wts   = (const float*)d_in[6];
    char* ws = (char*)d_ws;
    float*    ws_part = (float*)(ws + O_PART);
    float*    ws_g    = (float*)(ws + O_G);
    ushort_t* ws_A    = (ushort_t*)(ws + O_A);
    ushort_t* ws_B    = (ushort_t*)(ws + O_B);
    float* out = (float*)d_out;

    k_pre<<<dim3(PREP_BLKS + JS1_BLKS), dim3(256), 0, stream>>>(pdirs, sdirs, vtemp, jreg, ws_B, ws_part);
    k_chain<<<dim3(N_B / 4), dim3(256), 0, stream>>>(beta, pose, ws_part, ws_g, ws_A);
    k_gl<<<dim3(RPAD / 192, N_B / 64), dim3(256), 0, stream>>>(ws_A, ws_B, vtemp, wts, ws_g, out);
}

// Round 4
// 150.767 us; speedup vs baseline: 1.2883x; 1.2883x over previous
//
#include <hip/hip_runtime.h>

#define V_CNT 6890
#define N_B 512
#define NP 207          // (24-1)*9
#define KPAD 224        // 207 lrotmin + 10 beta + 7 zero
#define RTOT 20670      // V*3
#define RPAD 20736      // 162 * 128
#define PREP_BLKS 2268  // RPAD*KPAD/8/256
#define JS1_BLKS 384    // 16 chunks x 24 joints
#define W_BLKS 27       // 6912/256

typedef unsigned short ushort_t;
typedef __attribute__((ext_vector_type(4))) float f32x4;
typedef __attribute__((ext_vector_type(8))) short s16x8;
typedef __attribute__((ext_vector_type(4))) float f4a;

// ws layout (bytes)
#define O_PART 0u         // 24*16*33 f32 = 50688
#define O_G2   65536u     // 512*512 bf16 = 524288   (G' in B-fragment order)
#define O_A    655360u    // 512*224 bf16 = 229376
#define O_W    917504u    // 6912*32 bf16 = 442368   (weights padded)
#define O_B    1441792u   // 20736*224 bf16 = 9289728
#define O_PB   10747904u  // 512*20736 bf16 = 21233664 (v_posed, vtemp fused)

__device__ __constant__ int PAR[24] = {0,0,0,0,1,2,3,4,5,6,7,8,9,9,9,12,13,14,16,17,18,19,20,21};

__device__ __forceinline__ ushort_t f2bf(float f) {
    union { float f; unsigned u; } x; x.f = f;
    unsigned u = x.u + 0x7fffu + ((x.u >> 16) & 1u);
    return (ushort_t)(u >> 16);
}
__device__ __forceinline__ float bf2f(ushort_t h) {
    union { unsigned u; float f; } x; x.u = ((unsigned)h) << 16;
    return x.f;
}

// ---------- K1: B-prep | JS/JT partials | W-pad prep (segmented by blockIdx) ----------
__global__ __launch_bounds__(256) void k_pre(const float* __restrict__ pdirs,
                                             const float* __restrict__ sdirs,
                                             const float* __restrict__ vtemp,
                                             const float* __restrict__ jreg,
                                             const float* __restrict__ wts,
                                             ushort_t* __restrict__ Bm,
                                             float* __restrict__ part,
                                             ushort_t* __restrict__ Wp) {
    int b = blockIdx.x;
    int tid = threadIdx.x;
    if (b < PREP_BLKS) {
        int g = b * 256 + tid;           // 0 .. 580607
        int r = g / 28;                  // row 0..20735
        int k0 = (g - r * 28) * 8;       // 0,8,...,216
        s16x8 pk;
        if (r < RTOT) {
            const float* pr = pdirs + (size_t)r * NP;
            const float* sr = sdirs + (size_t)r * 10;
#pragma unroll
            for (int i = 0; i < 8; i++) {
                int k = k0 + i;
                float v = 0.f;
                if (k < NP) v = pr[k];
                else if (k < 217) v = sr[k - NP];
                pk[i] = (short)f2bf(v);
            }
        } else {
#pragma unroll
            for (int i = 0; i < 8; i++) pk[i] = 0;
        }
        *(s16x8*)(Bm + (size_t)r * KPAD + k0) = pk;
    } else if (b < PREP_BLKS + JS1_BLKS) {
        int b2 = b - PREP_BLKS;          // j*16 + ch
        int ch = b2 & 15;
        int j = b2 >> 4;
        int v0 = ch * 432;
        int vend = v0 + 432; if (vend > V_CNT) vend = V_CNT;
        float acc[33];
#pragma unroll
        for (int i = 0; i < 33; i++) acc[i] = 0.f;
        for (int v = v0 + tid; v < vend; v += 256) {
            float r = jreg[j * V_CNT + v];
            const float* sd = sdirs + v * 30;
#pragma unroll
            for (int i = 0; i < 30; i++) acc[i] += r * sd[i];
            acc[30] += r * vtemp[v * 3 + 0];
            acc[31] += r * vtemp[v * 3 + 1];
            acc[32] += r * vtemp[v * 3 + 2];
        }
#pragma unroll
        for (int off = 32; off > 0; off >>= 1) {
#pragma unroll
            for (int i = 0; i < 33; i++) acc[i] += __shfl_down(acc[i], off);
        }
        __shared__ float red[4][33];
        int w = tid >> 6, lane = tid & 63;
        if (lane == 0) {
#pragma unroll
            for (int i = 0; i < 33; i++) red[w][i] = acc[i];
        }
        __syncthreads();
        if (tid < 33) {
            float s = red[0][tid] + red[1][tid] + red[2][tid] + red[3][tid];
            part[b2 * 33 + tid] = s;
        }
    } else {
        int v = (b - PREP_BLKS - JS1_BLKS) * 256 + tid;   // 0..6911
        ushort_t o[32];
        if (v < V_CNT) {
            const float* wr = wts + v * 24;
#pragma unroll
            for (int j = 0; j < 24; j++) o[j] = f2bf(wr[j]);
        } else {
#pragma unroll
            for (int j = 0; j < 24; j++) o[j] = 0;
        }
#pragma unroll
        for (int j = 24; j < 32; j++) o[j] = 0;
#pragma unroll
        for (int q = 0; q < 4; q++)
            *(s16x8*)(Wp + (size_t)v * 32 + q * 8) = *(s16x8*)&o[q * 8];
    }
}

// ---------- K2: js2 reduce + per-n chain (4 n/block) -> G2pack bf16, A bf16 ----------
__global__ __launch_bounds__(256) void k_chain(const float* __restrict__ beta,
                                               const float* __restrict__ pose,
                                               const float* __restrict__ part,
                                               ushort_t* __restrict__ G2,
                                               ushort_t* __restrict__ Am) {
    __shared__ float JSl[720];
    __shared__ float JTl[72];
    __shared__ float Rl[4][24][9];
    __shared__ float Jl[4][24][3];
    __shared__ float Tm[4][24][16];
    __shared__ float G[4][24][16];
    __shared__ float Gp[4][24][12];
    int tid = threadIdx.x;

    // fused js2: reduce 16 chunk-partials
    for (int t = tid; t < 792; t += 256) {
        int j = t / 33, i = t - j * 33;
        float s = 0.f;
#pragma unroll
        for (int c = 0; c < 16; c++) s += part[(j * 16 + c) * 33 + i];
        if (i < 30) JSl[j * 30 + i] = s;
        else        JTl[j * 3 + (i - 30)] = s;
    }
    __syncthreads();

    int sub = tid >> 6, lane = tid & 63;
    int n = blockIdx.x * 4 + sub;

    if (lane < 24) {
        int t = lane;
        float x = pose[n * 72 + t * 3 + 0];
        float y = pose[n * 72 + t * 3 + 1];
        float z = pose[n * 72 + t * 3 + 2];
        float th = sqrtf(x * x + y * y + z * z) + 1e-8f;
        float inv = 1.f / th;
        float rx = x * inv, ry = y * inv, rz = z * inv;
        float c = cosf(th), s = sinf(th), omc = 1.f - c;
        Rl[sub][t][0] = c + omc * rx * rx;
        Rl[sub][t][1] = omc * rx * ry - s * rz;
        Rl[sub][t][2] = omc * rx * rz + s * ry;
        Rl[sub][t][3] = omc * ry * rx + s * rz;
        Rl[sub][t][4] = c + omc * ry * ry;
        Rl[sub][t][5] = omc * ry * rz - s * rx;
        Rl[sub][t][6] = omc * rz * rx - s * ry;
        Rl[sub][t][7] = omc * rz * ry + s * rx;
        Rl[sub][t][8] = c + omc * rz * rz;
#pragma unroll
        for (int cc = 0; cc < 3; cc++) {
            float a = JTl[t * 3 + cc];
#pragma unroll
            for (int b = 0; b < 10; b++) a += beta[n * 10 + b] * JSl[(t * 3 + cc) * 10 + b];
            Jl[sub][t][cc] = a;
        }
    }
    __syncthreads();
    if (lane < 24) {
        int t = lane;
        int p = PAR[t];
        float tx, ty, tz;
        if (t == 0) { tx = Jl[sub][0][0]; ty = Jl[sub][0][1]; tz = Jl[sub][0][2]; }
        else { tx = Jl[sub][t][0] - Jl[sub][p][0]; ty = Jl[sub][t][1] - Jl[sub][p][1]; tz = Jl[sub][t][2] - Jl[sub][p][2]; }
        Tm[sub][t][0] = Rl[sub][t][0]; Tm[sub][t][1] = Rl[sub][t][1]; Tm[sub][t][2]  = Rl[sub][t][2]; Tm[sub][t][3]  = tx;
        Tm[sub][t][4] = Rl[sub][t][3]; Tm[sub][t][5] = Rl[sub][t][4]; Tm[sub][t][6]  = Rl[sub][t][5]; Tm[sub][t][7]  = ty;
        Tm[sub][t][8] = Rl[sub][t][6]; Tm[sub][t][9] = Rl[sub][t][7]; Tm[sub][t][10] = Rl[sub][t][8]; Tm[sub][t][11] = tz;
        Tm[sub][t][12] = 0.f; Tm[sub][t][13] = 0.f; Tm[sub][t][14] = 0.f; Tm[sub][t][15] = 1.f;
    }
    __syncthreads();
    if (lane < 16) G[sub][0][lane] = Tm[sub][0][lane];
    __syncthreads();
    for (int i = 1; i < 24; i++) {
        int p = PAR[i];
        if (lane < 16) {
            int a = lane >> 2, bb = lane & 3;
            float s = G[sub][p][a * 4 + 0] * Tm[sub][i][0 * 4 + bb]
                    + G[sub][p][a * 4 + 1] * Tm[sub][i][1 * 4 + bb]
                    + G[sub][p][a * 4 + 2] * Tm[sub][i][2 * 4 + bb]
                    + G[sub][p][a * 4 + 3] * Tm[sub][i][3 * 4 + bb];
            G[sub][i][lane] = s;
        }
        __syncthreads();
    }
    if (lane < 24) {
        int t = lane;
        float jx = Jl[sub][t][0], jy = Jl[sub][t][1], jz = Jl[sub][t][2];
#pragma unroll
        for (int a = 0; a < 3; a++) {
            float g0 = G[sub][t][a * 4 + 0], g1 = G[sub][t][a * 4 + 1];
            float g2 = G[sub][t][a * 4 + 2], g3 = G[sub][t][a * 4 + 3];
            Gp[sub][t][a * 4 + 0] = g0;
            Gp[sub][t][a * 4 + 1] = g1;
            Gp[sub][t][a * 4 + 2] = g2;
            Gp[sub][t][a * 4 + 3] = g3 - (g0 * jx + g1 * jy + g2 * jz);
        }
    }
    __syncthreads();
    // pack G' into B-fragment order: lane holds B[k=quad*8+jj][col=lm]
    {
        int quad = lane >> 4, lm = lane & 15;
        s16x8 pk;
#pragma unroll
        for (int jj = 0; jj < 8; jj++) {
            int joint = quad * 8 + jj;
            float val = (joint < 24 && lm < 12) ? Gp[sub][joint][lm] : 0.f;
            pk[jj] = (short)f2bf(val);
        }
        *(s16x8*)(G2 + (size_t)n * 512 + lane * 8) = pk;
    }
    // A row: [lrotmin(207) | beta(10) | 0(7)] bf16
    for (int idx = lane; idx < KPAD; idx += 64) {
        float val;
        if (idx < NP) {
            int j = 1 + idx / 9;
            int e = idx - (j - 1) * 9;
            float d = (e == 0 || e == 4 || e == 8) ? 1.f : 0.f;
            val = Rl[sub][j][e] - d;
        } else if (idx < 217) {
            val = beta[n * 10 + (idx - NP)];
        } else val = 0.f;
        Am[n * KPAD + idx] = f2bf(val);
    }
}

// ---------- K3: MFMA GEMM pb[512][RPAD] = A x B^T, + vtemp fused (pb = v_posed) ----------
// block tile 64(n) x 128(r); 4 waves, wave tile 32x64
__global__ __launch_bounds__(256) void k_gemm(const ushort_t* __restrict__ A,
                                              const ushort_t* __restrict__ B,
                                              const float* __restrict__ vtemp,
                                              ushort_t* __restrict__ C) {
    __shared__ __align__(16) ushort_t a_lds[64 * 40];   // pad 32->40
    __shared__ __align__(16) ushort_t b_lds[128 * 40];
    int tid = threadIdx.x;
    int rblk = blockIdx.x * 128;
    int n0 = blockIdx.y * 64;
    int w = tid >> 6, lane = tid & 63;
    int quad = lane >> 4, lm = lane & 15;
    int m0w = (w >> 1) * 32, r0w = (w & 1) * 64;

    f32x4 acc[2][4];
#pragma unroll
    for (int a = 0; a < 2; a++)
#pragma unroll
        for (int b = 0; b < 4; b++) acc[a][b] = (f32x4)0.f;

    int srow = tid >> 2, koff = (tid & 3) * 8;
    const ushort_t* ag  = A + (n0 + srow) * KPAD + koff;
    const ushort_t* bg1 = B + (size_t)(rblk + srow) * KPAD + koff;
    const ushort_t* bg2 = B + (size_t)(rblk + srow + 64) * KPAD + koff;

#pragma unroll 1
    for (int kc = 0; kc < 7; kc++) {
        s16x8 av  = *(const s16x8*)(ag  + kc * 32);
        s16x8 bv1 = *(const s16x8*)(bg1 + kc * 32);
        s16x8 bv2 = *(const s16x8*)(bg2 + kc * 32);
        __syncthreads();
        *(s16x8*)&a_lds[srow * 40 + koff] = av;
        *(s16x8*)&b_lds[srow * 40 + koff] = bv1;
        *(s16x8*)&b_lds[(srow + 64) * 40 + koff] = bv2;
        __syncthreads();
        s16x8 af[2], bf[4];
#pragma unroll
        for (int mt = 0; mt < 2; mt++)
            af[mt] = *(const s16x8*)&a_lds[(m0w + mt * 16 + lm) * 40 + quad * 8];
#pragma unroll
        for (int rt = 0; rt < 4; rt++)
            bf[rt] = *(const s16x8*)&b_lds[(r0w + rt * 16 + lm) * 40 + quad * 8];
#pragma unroll
        for (int mt = 0; mt < 2; mt++)
#pragma unroll
            for (int rt = 0; rt < 4; rt++)
                acc[mt][rt] = __builtin_amdgcn_mfma_f32_16x16x32_bf16(af[mt], bf[rt], acc[mt][rt], 0, 0, 0);
    }
#pragma unroll
    for (int mt = 0; mt < 2; mt++) {
#pragma unroll
        for (int rt = 0; rt < 4; rt++) {
            int col = rblk + r0w + rt * 16 + lm;
            float vt = (col < RTOT) ? vtemp[col] : 0.f;
#pragma unroll
            for (int i = 0; i < 4; i++) {
                int row = n0 + m0w + mt * 16 + quad * 4 + i;
                C[(size_t)row * RPAD + col] = f2bf(acc[mt][rt][i] + vt);
            }
        }
    }
}

// ---------- K4: MFMA LBS: T = W x G'  then apply to v_posed ----------
// grid (108 v-tiles of 64, 128 n-groups of 4), block 256 = 4 waves; wave = one n
__global__ __launch_bounds__(256) void k_lbs(const ushort_t* __restrict__ Wp,
                                             const ushort_t* __restrict__ G2,
                                             const ushort_t* __restrict__ pb,
                                             float* __restrict__ out) {
    __shared__ float T[4][64][19];
    int tid = threadIdx.x, w = tid >> 6, lane = tid & 63;
    int quad = lane >> 4, lm = lane & 15;
    int v0 = blockIdx.x * 64;
    int n = blockIdx.y * 4 + w;
    int v = v0 + lane;

    // v_posed early load (independent of MFMA)
    const ushort_t* pp = pb + (size_t)n * RPAD + v * 3;
    float px = bf2f(pp[0]), py = bf2f(pp[1]), pz = bf2f(pp[2]);

    s16x8 bfr = *(const s16x8*)(G2 + (size_t)n * 512 + lane * 8);
    f32x4 acc[4];
#pragma unroll
    for (int mt = 0; mt < 4; mt++) {
        s16x8 af = *(const s16x8*)(Wp + (size_t)(v0 + mt * 16 + lm) * 32 + quad * 8);
        acc[mt] = __builtin_amdgcn_mfma_f32_16x16x32_bf16(af, bfr, (f32x4)0.f, 0, 0, 0);
    }
    // transpose C: row (v-local) = mt*16 + quad*4 + i, col (q) = lm; stride 19 => <=2-way aliasing
#pragma unroll
    for (int mt = 0; mt < 4; mt++)
#pragma unroll
        for (int i = 0; i < 4; i++)
            T[w][mt * 16 + quad * 4 + i][lm] = acc[mt][i];
    __syncthreads();

    if (v < V_CNT) {
        const float* Tr = &T[w][lane][0];
        float o0 = Tr[3]  + Tr[0] * px + Tr[1] * py + Tr[2]  * pz;
        float o1 = Tr[7]  + Tr[4] * px + Tr[5] * py + Tr[6]  * pz;
        float o2 = Tr[11] + Tr[8] * px + Tr[9] * py + Tr[10] * pz;
        float* op = out + ((size_t)n * V_CNT + v) * 3;
        op[0] = o0; op[1] = o1; op[2] = o2;
    }
}

extern "C" void kernel_launch(void* const* d_in, const int* in_sizes, int n_in,
                              void* d_out, int out_size, void* d_ws, size_t ws_size,
                              hipStream_t stream) {
    const float* beta  = (const float*)d_in[0];
    const float* pose  = (const float*)d_in[1];
    const float* vtemp = (const float*)d_in[2];
    const float* sdirs = (const float*)d_in[3];
    const float* pdirs = (const float*)d_in[4];
    const float* jreg  = (const float*)d_in[5];
    const float* wts   = (const float*)d_in[6];
    char* ws = (char*)d_ws;
    float*    ws_part = (float*)(ws + O_PART);
    ushort_t* ws_G2   = (ushort_t*)(ws + O_G2);
    ushort_t* ws_A    = (ushort_t*)(ws + O_A);
    ushort_t* ws_W    = (ushort_t*)(ws + O_W);
    ushort_t* ws_B    = (ushort_t*)(ws + O_B);
    ushort_t* ws_pb   = (ushort_t*)(ws + O_PB);
    float* out = (float*)d_out;

    k_pre<<<dim3(PREP_BLKS + JS1_BLKS + W_BLKS), dim3(256), 0, stream>>>(
        pdirs, sdirs, vtemp, jreg, wts, ws_B, ws_part, ws_W);
    k_chain<<<dim3(N_B / 4), dim3(256), 0, stream>>>(beta, pose, ws_part, ws_G2, ws_A);
    k_gemm<<<dim3(RPAD / 128, N_B / 64), dim3(256), 0, stream>>>(ws_A, ws_B, vtemp, ws_pb);
    k_lbs<<<dim3(108, N_B / 4), dim3(256), 0, stream>>>(ws_W, ws_G2, ws_pb, out);
}

// Round 5
// 148.121 us; speedup vs baseline: 1.3113x; 1.0179x over previous
//
#include <hip/hip_runtime.h>

#define V_CNT 6890
#define N_B 512
#define NP 207          // (24-1)*9
#define KPAD 224        // 207 lrotmin + 10 beta + 7 zero
#define RTOT 20670      // V*3
#define RPAD 20736      // 162 * 128
#define PREP_BLKS 2268  // RPAD*KPAD/8/256
#define JS1_BLKS 384    // 16 chunks x 24 joints
#define W_BLKS 27       // 6912/256

typedef unsigned short ushort_t;
typedef __attribute__((ext_vector_type(4))) float f32x4;
typedef __attribute__((ext_vector_type(8))) short s16x8;
typedef __attribute__((ext_vector_type(2))) float f32x2;

// ws layout (bytes)
#define O_PART 0u         // 24*16*33 f32 = 50688
#define O_G2   65536u     // 512*512 bf16 = 524288   (G' in B-fragment order)
#define O_A    655360u    // 512*224 bf16 = 229376
#define O_W    917504u    // 6912*32 bf16 = 442368   (weights padded)
#define O_B    1441792u   // 20736*224 bf16 = 9289728
#define O_PB   10747904u  // 512*20736 bf16 = 21233664 (v_posed, vtemp fused)

__device__ __constant__ int PAR[24] = {0,0,0,0,1,2,3,4,5,6,7,8,9,9,9,12,13,14,16,17,18,19,20,21};
// level-parallel chain schedule: 9 passes x up to 4 joints (depth of SMPL tree = 8)
__device__ __constant__ int LVL[36] = {
    1, 2, 3,-1,   4, 5, 6,-1,   7, 8, 9,-1,
   10,11,12,13,  14,-1,-1,-1,  15,16,17,-1,
   18,19,-1,-1,  20,21,-1,-1,  22,23,-1,-1};

__device__ __forceinline__ ushort_t f2bf(float f) {
    union { float f; unsigned u; } x; x.f = f;
    unsigned u = x.u + 0x7fffu + ((x.u >> 16) & 1u);
    return (ushort_t)(u >> 16);
}
__device__ __forceinline__ float bf2f(ushort_t h) {
    union { unsigned u; float f; } x; x.u = ((unsigned)h) << 16;
    return x.f;
}

// ---------- K1: B-prep | JS/JT partials | W-pad prep (segmented by blockIdx) ----------
__global__ __launch_bounds__(256) void k_pre(const float* __restrict__ pdirs,
                                             const float* __restrict__ sdirs,
                                             const float* __restrict__ vtemp,
                                             const float* __restrict__ jreg,
                                             const float* __restrict__ wts,
                                             ushort_t* __restrict__ Bm,
                                             float* __restrict__ part,
                                             ushort_t* __restrict__ Wp) {
    int b = blockIdx.x;
    int tid = threadIdx.x;
    if (b < PREP_BLKS) {
        int g = b * 256 + tid;           // 0 .. 580607
        int r = g / 28;                  // row 0..20735
        int k0 = (g - r * 28) * 8;       // 0,8,...,216
        s16x8 pk;
        if (r < RTOT) {
            const float* pr = pdirs + (size_t)r * NP;
            const float* sr = sdirs + (size_t)r * 10;
#pragma unroll
            for (int i = 0; i < 8; i++) {
                int k = k0 + i;
                float v = 0.f;
                if (k < NP) v = pr[k];
                else if (k < 217) v = sr[k - NP];
                pk[i] = (short)f2bf(v);
            }
        } else {
#pragma unroll
            for (int i = 0; i < 8; i++) pk[i] = 0;
        }
        *(s16x8*)(Bm + (size_t)r * KPAD + k0) = pk;
    } else if (b < PREP_BLKS + JS1_BLKS) {
        int b2 = b - PREP_BLKS;          // j*16 + ch
        int ch = b2 & 15;
        int j = b2 >> 4;
        int v0 = ch * 432;
        int vend = v0 + 432; if (vend > V_CNT) vend = V_CNT;
        float acc[33];
#pragma unroll
        for (int i = 0; i < 33; i++) acc[i] = 0.f;
        for (int v = v0 + tid; v < vend; v += 256) {
            float r = jreg[j * V_CNT + v];
            const float* sd = sdirs + v * 30;
#pragma unroll
            for (int i = 0; i < 30; i++) acc[i] += r * sd[i];
            acc[30] += r * vtemp[v * 3 + 0];
            acc[31] += r * vtemp[v * 3 + 1];
            acc[32] += r * vtemp[v * 3 + 2];
        }
#pragma unroll
        for (int off = 32; off > 0; off >>= 1) {
#pragma unroll
            for (int i = 0; i < 33; i++) acc[i] += __shfl_down(acc[i], off);
        }
        __shared__ float red[4][33];
        int w = tid >> 6, lane = tid & 63;
        if (lane == 0) {
#pragma unroll
            for (int i = 0; i < 33; i++) red[w][i] = acc[i];
        }
        __syncthreads();
        if (tid < 33) {
            float s = red[0][tid] + red[1][tid] + red[2][tid] + red[3][tid];
            part[b2 * 33 + tid] = s;
        }
    } else {
        int v = (b - PREP_BLKS - JS1_BLKS) * 256 + tid;   // 0..6911
        ushort_t o[32];
        if (v < V_CNT) {
            const float* wr = wts + v * 24;
#pragma unroll
            for (int j = 0; j < 24; j++) o[j] = f2bf(wr[j]);
        } else {
#pragma unroll
            for (int j = 0; j < 24; j++) o[j] = 0;
        }
#pragma unroll
        for (int j = 24; j < 32; j++) o[j] = 0;
#pragma unroll
        for (int q = 0; q < 4; q++)
            *(s16x8*)(Wp + (size_t)v * 32 + q * 8) = *(s16x8*)&o[q * 8];
    }
}

// ---------- K2: js2 reduce + per-n chain (2 n/block, level-parallel) ----------
__global__ __launch_bounds__(128) void k_chain(const float* __restrict__ beta,
                                               const float* __restrict__ pose,
                                               const float* __restrict__ part,
                                               ushort_t* __restrict__ G2,
                                               ushort_t* __restrict__ Am) {
    __shared__ float JSl[720];
    __shared__ float JTl[72];
    __shared__ float Rl[2][24][9];
    __shared__ float Jl[2][24][3];
    __shared__ float Tm[2][24][16];
    __shared__ float G[2][24][16];
    __shared__ float Gp[2][24][12];
    int tid = threadIdx.x;

    // fused js2: reduce 16 chunk-partials
    for (int t = tid; t < 792; t += 128) {
        int j = t / 33, i = t - j * 33;
        float s = 0.f;
#pragma unroll
        for (int c = 0; c < 16; c++) s += part[(j * 16 + c) * 33 + i];
        if (i < 30) JSl[j * 30 + i] = s;
        else        JTl[j * 3 + (i - 30)] = s;
    }
    __syncthreads();

    int sub = tid >> 6, lane = tid & 63;
    int n = blockIdx.x * 2 + sub;

    if (lane < 24) {
        int t = lane;
        float x = pose[n * 72 + t * 3 + 0];
        float y = pose[n * 72 + t * 3 + 1];
        float z = pose[n * 72 + t * 3 + 2];
        float th = sqrtf(x * x + y * y + z * z) + 1e-8f;
        float inv = 1.f / th;
        float rx = x * inv, ry = y * inv, rz = z * inv;
        float c = cosf(th), s = sinf(th), omc = 1.f - c;
        Rl[sub][t][0] = c + omc * rx * rx;
        Rl[sub][t][1] = omc * rx * ry - s * rz;
        Rl[sub][t][2] = omc * rx * rz + s * ry;
        Rl[sub][t][3] = omc * ry * rx + s * rz;
        Rl[sub][t][4] = c + omc * ry * ry;
        Rl[sub][t][5] = omc * ry * rz - s * rx;
        Rl[sub][t][6] = omc * rz * rx - s * ry;
        Rl[sub][t][7] = omc * rz * ry + s * rx;
        Rl[sub][t][8] = c + omc * rz * rz;
#pragma unroll
        for (int cc = 0; cc < 3; cc++) {
            float a = JTl[t * 3 + cc];
#pragma unroll
            for (int b = 0; b < 10; b++) a += beta[n * 10 + b] * JSl[(t * 3 + cc) * 10 + b];
            Jl[sub][t][cc] = a;
        }
    }
    __syncthreads();
    if (lane < 24) {
        int t = lane;
        int p = PAR[t];
        float tx, ty, tz;
        if (t == 0) { tx = Jl[sub][0][0]; ty = Jl[sub][0][1]; tz = Jl[sub][0][2]; }
        else { tx = Jl[sub][t][0] - Jl[sub][p][0]; ty = Jl[sub][t][1] - Jl[sub][p][1]; tz = Jl[sub][t][2] - Jl[sub][p][2]; }
        Tm[sub][t][0] = Rl[sub][t][0]; Tm[sub][t][1] = Rl[sub][t][1]; Tm[sub][t][2]  = Rl[sub][t][2]; Tm[sub][t][3]  = tx;
        Tm[sub][t][4] = Rl[sub][t][3]; Tm[sub][t][5] = Rl[sub][t][4]; Tm[sub][t][6]  = Rl[sub][t][5]; Tm[sub][t][7]  = ty;
        Tm[sub][t][8] = Rl[sub][t][6]; Tm[sub][t][9] = Rl[sub][t][7]; Tm[sub][t][10] = Rl[sub][t][8]; Tm[sub][t][11] = tz;
        Tm[sub][t][12] = 0.f; Tm[sub][t][13] = 0.f; Tm[sub][t][14] = 0.f; Tm[sub][t][15] = 1.f;
    }
    __syncthreads();
    if (lane < 16) G[sub][0][lane] = Tm[sub][0][lane];
    __syncthreads();
    // level-parallel chain: 9 passes, lane = slot*16 + el
#pragma unroll
    for (int p9 = 0; p9 < 9; p9++) {
        int slot = lane >> 4, el = lane & 15;
        int j = LVL[p9 * 4 + slot];
        if (j >= 0) {
            int par = PAR[j];
            int a = el >> 2, bb = el & 3;
            float s = G[sub][par][a * 4 + 0] * Tm[sub][j][0 * 4 + bb]
                    + G[sub][par][a * 4 + 1] * Tm[sub][j][1 * 4 + bb]
                    + G[sub][par][a * 4 + 2] * Tm[sub][j][2 * 4 + bb]
                    + G[sub][par][a * 4 + 3] * Tm[sub][j][3 * 4 + bb];
            G[sub][j][el] = s;
        }
        __syncthreads();
    }
    if (lane < 24) {
        int t = lane;
        float jx = Jl[sub][t][0], jy = Jl[sub][t][1], jz = Jl[sub][t][2];
#pragma unroll
        for (int a = 0; a < 3; a++) {
            float g0 = G[sub][t][a * 4 + 0], g1 = G[sub][t][a * 4 + 1];
            float g2 = G[sub][t][a * 4 + 2], g3 = G[sub][t][a * 4 + 3];
            Gp[sub][t][a * 4 + 0] = g0;
            Gp[sub][t][a * 4 + 1] = g1;
            Gp[sub][t][a * 4 + 2] = g2;
            Gp[sub][t][a * 4 + 3] = g3 - (g0 * jx + g1 * jy + g2 * jz);
        }
    }
    __syncthreads();
    // pack G' into B-fragment order: lane holds B[k=quad*8+jj][col=lm]
    {
        int quad = lane >> 4, lm = lane & 15;
        s16x8 pk;
#pragma unroll
        for (int jj = 0; jj < 8; jj++) {
            int joint = quad * 8 + jj;
            float val = (joint < 24 && lm < 12) ? Gp[sub][joint][lm] : 0.f;
            pk[jj] = (short)f2bf(val);
        }
        *(s16x8*)(G2 + (size_t)n * 512 + lane * 8) = pk;
    }
    // A row: [lrotmin(207) | beta(10) | 0(7)] bf16
    for (int idx = lane; idx < KPAD; idx += 64) {
        float val;
        if (idx < NP) {
            int j = 1 + idx / 9;
            int e = idx - (j - 1) * 9;
            float d = (e == 0 || e == 4 || e == 8) ? 1.f : 0.f;
            val = Rl[sub][j][e] - d;
        } else if (idx < 217) {
            val = beta[n * 10 + (idx - NP)];
        } else val = 0.f;
        Am[n * KPAD + idx] = f2bf(val);
    }
}

// ---------- K3: MFMA GEMM pb[512][RPAD] = A x B^T, + vtemp fused (pb = v_posed) ----------
// block tile 128(n) x 128(r); 4 waves (2x2), wave tile 64x64
__global__ __launch_bounds__(256) void k_gemm(const ushort_t* __restrict__ A,
                                              const ushort_t* __restrict__ B,
                                              const float* __restrict__ vtemp,
                                              ushort_t* __restrict__ C) {
    __shared__ __align__(16) ushort_t a_lds[128 * 40];   // k-chunk 32, pad->40
    __shared__ __align__(16) ushort_t b_lds[128 * 40];
    int tid = threadIdx.x;
    int rblk = blockIdx.x * 128;
    int n0 = blockIdx.y * 128;
    int w = tid >> 6, lane = tid & 63;
    int quad = lane >> 4, lm = lane & 15;
    int m0w = (w >> 1) * 64, r0w = (w & 1) * 64;

    f32x4 acc[4][4];
#pragma unroll
    for (int a = 0; a < 4; a++)
#pragma unroll
        for (int b = 0; b < 4; b++) acc[a][b] = (f32x4)0.f;

    int srow = tid >> 1, koff = (tid & 1) * 16;
    const ushort_t* ag = A + (size_t)(n0 + srow) * KPAD + koff;
    const ushort_t* bg = B + (size_t)(rblk + srow) * KPAD + koff;

#pragma unroll 1
    for (int kc = 0; kc < 7; kc++) {
        s16x8 av0 = *(const s16x8*)(ag + kc * 32);
        s16x8 av1 = *(const s16x8*)(ag + kc * 32 + 8);
        s16x8 bv0 = *(const s16x8*)(bg + kc * 32);
        s16x8 bv1 = *(const s16x8*)(bg + kc * 32 + 8);
        __syncthreads();
        *(s16x8*)&a_lds[srow * 40 + koff] = av0;
        *(s16x8*)&a_lds[srow * 40 + koff + 8] = av1;
        *(s16x8*)&b_lds[srow * 40 + koff] = bv0;
        *(s16x8*)&b_lds[srow * 40 + koff + 8] = bv1;
        __syncthreads();
        s16x8 af[4], bf[4];
#pragma unroll
        for (int mt = 0; mt < 4; mt++)
            af[mt] = *(const s16x8*)&a_lds[(m0w + mt * 16 + lm) * 40 + quad * 8];
#pragma unroll
        for (int rt = 0; rt < 4; rt++)
            bf[rt] = *(const s16x8*)&b_lds[(r0w + rt * 16 + lm) * 40 + quad * 8];
#pragma unroll
        for (int mt = 0; mt < 4; mt++)
#pragma unroll
            for (int rt = 0; rt < 4; rt++)
                acc[mt][rt] = __builtin_amdgcn_mfma_f32_16x16x32_bf16(af[mt], bf[rt], acc[mt][rt], 0, 0, 0);
    }
#pragma unroll
    for (int mt = 0; mt < 4; mt++) {
#pragma unroll
        for (int rt = 0; rt < 4; rt++) {
            int col = rblk + r0w + rt * 16 + lm;
            float vt = (col < RTOT) ? vtemp[col] : 0.f;
#pragma unroll
            for (int i = 0; i < 4; i++) {
                int row = n0 + m0w + mt * 16 + quad * 4 + i;
                C[(size_t)row * RPAD + col] = f2bf(acc[mt][rt][i] + vt);
            }
        }
    }
}

// ---------- K4: MFMA LBS: T = W x G', apply to v_posed; zero block barriers ----------
// grid (27 v-tiles of 256, 128 n-groups of 4); wave = one n sweeping 4 v-subtiles of 64
__global__ __launch_bounds__(256) void k_lbs(const ushort_t* __restrict__ Wp,
                                             const ushort_t* __restrict__ G2,
                                             const ushort_t* __restrict__ pb,
                                             float* __restrict__ out) {
    __shared__ float T[4][64][19];     // wave-private slice
    __shared__ float ost[4][192];      // wave-private output staging
    int tid = threadIdx.x, w = tid >> 6, lane = tid & 63;
    int quad = lane >> 4, lm = lane & 15;
    int v0 = blockIdx.x * 256;
    int n = blockIdx.y * 4 + w;

    s16x8 bfr = *(const s16x8*)(G2 + (size_t)n * 512 + lane * 8);
    const ushort_t* pbn = pb + (size_t)n * RPAD;

#pragma unroll 1
    for (int s = 0; s < 4; s++) {
        int vs = v0 + s * 64;
        // v_posed for this lane's vertex (independent of MFMA)
        const ushort_t* pp = pbn + (vs + lane) * 3;
        float px = bf2f(pp[0]), py = bf2f(pp[1]), pz = bf2f(pp[2]);

        f32x4 acc[4];
#pragma unroll
        for (int mt = 0; mt < 4; mt++) {
            s16x8 af = *(const s16x8*)(Wp + (size_t)(vs + mt * 16 + lm) * 32 + quad * 8);
            acc[mt] = __builtin_amdgcn_mfma_f32_16x16x32_bf16(af, bfr, (f32x4)0.f, 0, 0, 0);
        }
        // wave-private transpose (stride 19: reads conflict-free, writes ~3-way)
#pragma unroll
        for (int mt = 0; mt < 4; mt++)
#pragma unroll
            for (int i = 0; i < 4; i++)
                T[w][mt * 16 + quad * 4 + i][lm] = acc[mt][i];

        const float* Tr = &T[w][lane][0];
        float o0 = Tr[3]  + Tr[0] * px + Tr[1] * py + Tr[2]  * pz;
        float o1 = Tr[7]  + Tr[4] * px + Tr[5] * py + Tr[6]  * pz;
        float o2 = Tr[11] + Tr[8] * px + Tr[9] * py + Tr[10] * pz;
        ost[w][lane * 3 + 0] = o0;
        ost[w][lane * 3 + 1] = o1;
        ost[w][lane * 3 + 2] = o2;

        int cnt = V_CNT - vs; if (cnt > 64) cnt = 64;
        if (cnt > 0) {
            int nh = (cnt * 3) >> 1;   // float2 count (cnt*3 is even for cnt in {64,42})
            float* obase = out + ((size_t)n * V_CNT + vs) * 3;
            for (int j2 = lane; j2 < nh; j2 += 64)
                *(f32x2*)(obase + j2 * 2) = *(const f32x2*)&ost[w][j2 * 2];
        }
    }
}

extern "C" void kernel_launch(void* const* d_in, const int* in_sizes, int n_in,
                              void* d_out, int out_size, void* d_ws, size_t ws_size,
                              hipStream_t stream) {
    const float* beta  = (const float*)d_in[0];
    const float* pose  = (const float*)d_in[1];
    const float* vtemp = (const float*)d_in[2];
    const float* sdirs = (const float*)d_in[3];
    const float* pdirs = (const float*)d_in[4];
    const float* jreg  = (const float*)d_in[5];
    const float* wts   = (const float*)d_in[6];
    char* ws = (char*)d_ws;
    float*    ws_part = (float*)(ws + O_PART);
    ushort_t* ws_G2   = (ushort_t*)(ws + O_G2);
    ushort_t* ws_A    = (ushort_t*)(ws + O_A);
    ushort_t* ws_W    = (ushort_t*)(ws + O_W);
    ushort_t* ws_B    = (ushort_t*)(ws + O_B);
    ushort_t* ws_pb   = (ushort_t*)(ws + O_PB);
    float* out = (float*)d_out;

    k_pre<<<dim3(PREP_BLKS + JS1_BLKS + W_BLKS), dim3(256), 0, stream>>>(
        pdirs, sdirs, vtemp, jreg, wts, ws_B, ws_part, ws_W);
    k_chain<<<dim3(N_B / 2), dim3(128), 0, stream>>>(beta, pose, ws_part, ws_G2, ws_A);
    k_gemm<<<dim3(RPAD / 128, N_B / 128), dim3(256), 0, stream>>>(ws_A, ws_B, vtemp, ws_pb);
    k_lbs<<<dim3(27, N_B / 4), dim3(256), 0, stream>>>(ws_W, ws_G2, ws_pb, out);
}

// Round 6
// 141.954 us; speedup vs baseline: 1.3683x; 1.0434x over previous
//
#include <hip/hip_runtime.h>

#define V_CNT 6890
#define N_B 512
#define NP 207          // (24-1)*9
#define KPAD 224        // 207 lrotmin + 10 beta + 7 zero
#define RTOT 20670      // V*3
#define RPAD 20736      // 1296 rtiles * 16
#define PREP_BLKS 2268  // 1296*7*64/256
#define JS1_BLKS 192    // 8 chunks x 24 joints
#define W_BLKS 27       // 6912/256

typedef unsigned short ushort_t;
typedef __attribute__((ext_vector_type(4))) float f32x4;
typedef __attribute__((ext_vector_type(8))) short s16x8;
typedef __attribute__((ext_vector_type(2))) float f32x2;

// ws layout (bytes)
#define O_PART 0u         // 192*33 f32
#define O_G2   65536u     // 512*512 bf16 = 524288  (G' in B-fragment order)
#define O_A    655360u    // A_swz: 32 ntiles *7*64*8 bf16 = 229376
#define O_W    917504u    // 6912*32 bf16 = 442368
#define O_B    1441792u   // B_swz: 1296*7*64*8 bf16 = 9289728

__device__ __constant__ int PAR[24] = {0,0,0,0,1,2,3,4,5,6,7,8,9,9,9,12,13,14,16,17,18,19,20,21};
__device__ __constant__ int LVL[36] = {
    1, 2, 3,-1,   4, 5, 6,-1,   7, 8, 9,-1,
   10,11,12,13,  14,-1,-1,-1,  15,16,17,-1,
   18,19,-1,-1,  20,21,-1,-1,  22,23,-1,-1};

__device__ __forceinline__ ushort_t f2bf(float f) {
    union { float f; unsigned u; } x; x.f = f;
    unsigned u = x.u + 0x7fffu + ((x.u >> 16) & 1u);
    return (ushort_t)(u >> 16);
}
__device__ __forceinline__ float bf2f(ushort_t h) {
    union { unsigned u; float f; } x; x.u = ((unsigned)h) << 16;
    return x.f;
}

// ---------- K1: B_swz prep | JS/JT partials | W prep ----------
__global__ __launch_bounds__(256) void k_pre(const float* __restrict__ pdirs,
                                             const float* __restrict__ sdirs,
                                             const float* __restrict__ vtemp,
                                             const float* __restrict__ jreg,
                                             const float* __restrict__ wts,
                                             ushort_t* __restrict__ Bswz,
                                             float* __restrict__ part,
                                             ushort_t* __restrict__ Wp) {
    int b = blockIdx.x;
    int tid = threadIdx.x;
    if (b < PREP_BLKS) {
        // one thread = one 8-element fragment chunk; dest is contiguous (index g)
        int g = b * 256 + tid;          // ((rtile*7+kc)*64 + lane)
        int rtile = g / 448;
        int rem = g - rtile * 448;
        int kc = rem >> 6;
        int lane = rem & 63;
        int quad = lane >> 4, lm = lane & 15;
        int r = rtile * 16 + lm;
        int k0 = kc * 32 + quad * 8;
        s16x8 pk;
        if (r < RTOT) {
            const float* pr = pdirs + (size_t)r * NP;
            const float* sr = sdirs + (size_t)r * 10;
#pragma unroll
            for (int i = 0; i < 8; i++) {
                int k = k0 + i;
                float v = 0.f;
                if (k < NP) v = pr[k];
                else if (k < 217) v = sr[k - NP];
                pk[i] = (short)f2bf(v);
            }
        } else {
#pragma unroll
            for (int i = 0; i < 8; i++) pk[i] = 0;
        }
        *(s16x8*)(Bswz + (size_t)g * 8) = pk;
    } else if (b < PREP_BLKS + JS1_BLKS) {
        int b2 = b - PREP_BLKS;          // j*8 + ch
        int ch = b2 & 7;
        int j = b2 >> 3;
        int v0 = ch * 862;
        int vend = v0 + 862; if (vend > V_CNT) vend = V_CNT;
        float acc[33];
#pragma unroll
        for (int i = 0; i < 33; i++) acc[i] = 0.f;
        for (int v = v0 + tid; v < vend; v += 256) {
            float r = jreg[j * V_CNT + v];
            const float* sd = sdirs + v * 30;
#pragma unroll
            for (int i = 0; i < 30; i++) acc[i] += r * sd[i];
            acc[30] += r * vtemp[v * 3 + 0];
            acc[31] += r * vtemp[v * 3 + 1];
            acc[32] += r * vtemp[v * 3 + 2];
        }
#pragma unroll
        for (int off = 32; off > 0; off >>= 1) {
#pragma unroll
            for (int i = 0; i < 33; i++) acc[i] += __shfl_down(acc[i], off);
        }
        __shared__ float red[4][33];
        int w = tid >> 6, lane = tid & 63;
        if (lane == 0) {
#pragma unroll
            for (int i = 0; i < 33; i++) red[w][i] = acc[i];
        }
        __syncthreads();
        if (tid < 33) {
            float s = red[0][tid] + red[1][tid] + red[2][tid] + red[3][tid];
            part[b2 * 33 + tid] = s;
        }
    } else {
        int v = (b - PREP_BLKS - JS1_BLKS) * 256 + tid;   // 0..6911
        ushort_t o[32];
        if (v < V_CNT) {
            const float* wr = wts + v * 24;
#pragma unroll
            for (int j = 0; j < 24; j++) o[j] = f2bf(wr[j]);
        } else {
#pragma unroll
            for (int j = 0; j < 24; j++) o[j] = 0;
        }
#pragma unroll
        for (int j = 24; j < 32; j++) o[j] = 0;
#pragma unroll
        for (int q = 0; q < 4; q++)
            *(s16x8*)(Wp + (size_t)v * 32 + q * 8) = *(s16x8*)&o[q * 8];
    }
}

// ---------- K2: js2 + chain (2 n/block) -> G2 bf16, A_swz bf16 ----------
__global__ __launch_bounds__(128) void k_chain(const float* __restrict__ beta,
                                               const float* __restrict__ pose,
                                               const float* __restrict__ part,
                                               ushort_t* __restrict__ G2,
                                               ushort_t* __restrict__ Aswz) {
    __shared__ float JSl[720];
    __shared__ float JTl[72];
    __shared__ float Rl[2][24][9];
    __shared__ float Jl[2][24][3];
    __shared__ float Tm[2][24][16];
    __shared__ float G[2][24][16];
    __shared__ float Gp[2][24][12];
    int tid = threadIdx.x;

    for (int t = tid; t < 792; t += 128) {
        int j = t / 33, i = t - j * 33;
        float s = 0.f;
#pragma unroll
        for (int c = 0; c < 8; c++) s += part[(j * 8 + c) * 33 + i];
        if (i < 30) JSl[j * 30 + i] = s;
        else        JTl[j * 3 + (i - 30)] = s;
    }
    __syncthreads();

    int sub = tid >> 6, lane = tid & 63;
    int n = blockIdx.x * 2 + sub;

    if (lane < 24) {
        int t = lane;
        float x = pose[n * 72 + t * 3 + 0];
        float y = pose[n * 72 + t * 3 + 1];
        float z = pose[n * 72 + t * 3 + 2];
        float th = sqrtf(x * x + y * y + z * z) + 1e-8f;
        float inv = 1.f / th;
        float rx = x * inv, ry = y * inv, rz = z * inv;
        float c = cosf(th), s = sinf(th), omc = 1.f - c;
        Rl[sub][t][0] = c + omc * rx * rx;
        Rl[sub][t][1] = omc * rx * ry - s * rz;
        Rl[sub][t][2] = omc * rx * rz + s * ry;
        Rl[sub][t][3] = omc * ry * rx + s * rz;
        Rl[sub][t][4] = c + omc * ry * ry;
        Rl[sub][t][5] = omc * ry * rz - s * rx;
        Rl[sub][t][6] = omc * rz * rx - s * ry;
        Rl[sub][t][7] = omc * rz * ry + s * rx;
        Rl[sub][t][8] = c + omc * rz * rz;
#pragma unroll
        for (int cc = 0; cc < 3; cc++) {
            float a = JTl[t * 3 + cc];
#pragma unroll
            for (int b = 0; b < 10; b++) a += beta[n * 10 + b] * JSl[(t * 3 + cc) * 10 + b];
            Jl[sub][t][cc] = a;
        }
    }
    __syncthreads();
    if (lane < 24) {
        int t = lane;
        int p = PAR[t];
        float tx, ty, tz;
        if (t == 0) { tx = Jl[sub][0][0]; ty = Jl[sub][0][1]; tz = Jl[sub][0][2]; }
        else { tx = Jl[sub][t][0] - Jl[sub][p][0]; ty = Jl[sub][t][1] - Jl[sub][p][1]; tz = Jl[sub][t][2] - Jl[sub][p][2]; }
        Tm[sub][t][0] = Rl[sub][t][0]; Tm[sub][t][1] = Rl[sub][t][1]; Tm[sub][t][2]  = Rl[sub][t][2]; Tm[sub][t][3]  = tx;
        Tm[sub][t][4] = Rl[sub][t][3]; Tm[sub][t][5] = Rl[sub][t][4]; Tm[sub][t][6]  = Rl[sub][t][5]; Tm[sub][t][7]  = ty;
        Tm[sub][t][8] = Rl[sub][t][6]; Tm[sub][t][9] = Rl[sub][t][7]; Tm[sub][t][10] = Rl[sub][t][8]; Tm[sub][t][11] = tz;
        Tm[sub][t][12] = 0.f; Tm[sub][t][13] = 0.f; Tm[sub][t][14] = 0.f; Tm[sub][t][15] = 1.f;
    }
    __syncthreads();
    if (lane < 16) G[sub][0][lane] = Tm[sub][0][lane];
    __syncthreads();
#pragma unroll
    for (int p9 = 0; p9 < 9; p9++) {
        int slot = lane >> 4, el = lane & 15;
        int j = LVL[p9 * 4 + slot];
        if (j >= 0) {
            int par = PAR[j];
            int a = el >> 2, bb = el & 3;
            float s = G[sub][par][a * 4 + 0] * Tm[sub][j][0 * 4 + bb]
                    + G[sub][par][a * 4 + 1] * Tm[sub][j][1 * 4 + bb]
                    + G[sub][par][a * 4 + 2] * Tm[sub][j][2 * 4 + bb]
                    + G[sub][par][a * 4 + 3] * Tm[sub][j][3 * 4 + bb];
            G[sub][j][el] = s;
        }
        __syncthreads();
    }
    if (lane < 24) {
        int t = lane;
        float jx = Jl[sub][t][0], jy = Jl[sub][t][1], jz = Jl[sub][t][2];
#pragma unroll
        for (int a = 0; a < 3; a++) {
            float g0 = G[sub][t][a * 4 + 0], g1 = G[sub][t][a * 4 + 1];
            float g2 = G[sub][t][a * 4 + 2], g3 = G[sub][t][a * 4 + 3];
            Gp[sub][t][a * 4 + 0] = g0;
            Gp[sub][t][a * 4 + 1] = g1;
            Gp[sub][t][a * 4 + 2] = g2;
            Gp[sub][t][a * 4 + 3] = g3 - (g0 * jx + g1 * jy + g2 * jz);
        }
    }
    __syncthreads();
    // G2: B-fragment order for the T-MFMA
    {
        int quad = lane >> 4, lm = lane & 15;
        s16x8 pk;
#pragma unroll
        for (int jj = 0; jj < 8; jj++) {
            int joint = quad * 8 + jj;
            float val = (joint < 24 && lm < 12) ? Gp[sub][joint][lm] : 0.f;
            pk[jj] = (short)f2bf(val);
        }
        *(s16x8*)(G2 + (size_t)n * 512 + lane * 8) = pk;
    }
    // A_swz: A-fragment order; lane ℓ<28 -> (kc, quad) chunk of 8 k's
    if (lane < 28) {
        int kc = lane >> 2, quad2 = lane & 3;
        s16x8 pk;
#pragma unroll
        for (int j = 0; j < 8; j++) {
            int k = kc * 32 + quad2 * 8 + j;
            float val;
            if (k < NP) {
                int jo = 1 + k / 9;
                int e = k - (jo - 1) * 9;
                float d = (e == 0 || e == 4 || e == 8) ? 1.f : 0.f;
                val = Rl[sub][jo][e] - d;
            } else if (k < 217) {
                val = beta[n * 10 + (k - NP)];
            } else val = 0.f;
            pk[j] = (short)f2bf(val);
        }
        *(s16x8*)(Aswz + (((size_t)(n >> 4) * 7 + kc) * 64 + (quad2 * 16 + (n & 15))) * 8) = pk;
    }
}

// ---------- K3: fused barrier-free GEMM + LBS ----------
// grid (108 v-tiles of 64, 8 n-tiles of 64); 4 waves; wave = 32n x 96r (= 32 whole vertices)
__global__ __launch_bounds__(256) void k_fused(const ushort_t* __restrict__ Aswz,
                                               const ushort_t* __restrict__ Bswz,
                                               const ushort_t* __restrict__ Wp,
                                               const ushort_t* __restrict__ G2,
                                               const float* __restrict__ vtemp,
                                               float* __restrict__ out) {
    __shared__ ushort_t vp[4][96][34];    // v_posed^T per wave: [r-local][n-local]
    __shared__ float Tl[4][2][32][19];    // T transpose scratch (pair of n)
    __shared__ float ost[4][2][96];       // output staging
    int tid = threadIdx.x, w = tid >> 6, lane = tid & 63;
    int quad = lane >> 4, lm = lane & 15;
    int rh = w & 1, nh = w >> 1;
    int n_w = blockIdx.y * 64 + nh * 32;
    int vs_w = blockIdx.x * 64 + rh * 32;          // wave's first vertex
    int rtile0 = blockIdx.x * 12 + rh * 6;
    int ntile0 = blockIdx.y * 4 + nh * 2;

    f32x4 acc[2][6];
#pragma unroll
    for (int a = 0; a < 2; a++)
#pragma unroll
        for (int b = 0; b < 6; b++) acc[a][b] = (f32x4)0.f;

    // barrier-free K-loop: fragments direct from global (swizzled), 1-deep prefetch
    s16x8 af[2][2], bf[2][6];
#pragma unroll
    for (int mt = 0; mt < 2; mt++)
        af[0][mt] = *(const s16x8*)(Aswz + ((size_t)(ntile0 + mt) * 7 + 0) * 512 + lane * 8);
#pragma unroll
    for (int rt = 0; rt < 6; rt++)
        bf[0][rt] = *(const s16x8*)(Bswz + ((size_t)(rtile0 + rt) * 7 + 0) * 512 + lane * 8);
#pragma unroll
    for (int kc = 0; kc < 7; kc++) {
        int cur = kc & 1, nxt = cur ^ 1;
        if (kc < 6) {
#pragma unroll
            for (int mt = 0; mt < 2; mt++)
                af[nxt][mt] = *(const s16x8*)(Aswz + ((size_t)(ntile0 + mt) * 7 + kc + 1) * 512 + lane * 8);
#pragma unroll
            for (int rt = 0; rt < 6; rt++)
                bf[nxt][rt] = *(const s16x8*)(Bswz + ((size_t)(rtile0 + rt) * 7 + kc + 1) * 512 + lane * 8);
        }
#pragma unroll
        for (int mt = 0; mt < 2; mt++)
#pragma unroll
            for (int rt = 0; rt < 6; rt++)
                acc[mt][rt] = __builtin_amdgcn_mfma_f32_16x16x32_bf16(af[cur][mt], bf[cur][rt], acc[mt][rt], 0, 0, 0);
    }

    // stage v_posed = acc + vtemp into wave-private LDS (bf16, transposed [rl][nl])
    float vt[6];
#pragma unroll
    for (int rt = 0; rt < 6; rt++) {
        int col = blockIdx.x * 192 + rh * 96 + rt * 16 + lm;
        vt[rt] = (col < RTOT) ? vtemp[col] : 0.f;
    }
#pragma unroll
    for (int mt = 0; mt < 2; mt++) {
#pragma unroll
        for (int rt = 0; rt < 6; rt++) {
            int rl = rt * 16 + lm;
            int nl0 = mt * 16 + quad * 4;
            unsigned d0 = (unsigned)f2bf(acc[mt][rt][0] + vt[rt]) | ((unsigned)f2bf(acc[mt][rt][1] + vt[rt]) << 16);
            unsigned d1 = (unsigned)f2bf(acc[mt][rt][2] + vt[rt]) | ((unsigned)f2bf(acc[mt][rt][3] + vt[rt]) << 16);
            *(unsigned*)&vp[w][rl][nl0]     = d0;
            *(unsigned*)&vp[w][rl][nl0 + 2] = d1;
        }
    }

    // T-MFMA operand W (hoisted; rows = this wave's 32 vertices)
    s16x8 wf[2];
#pragma unroll
    for (int mt = 0; mt < 2; mt++)
        wf[mt] = *(const s16x8*)(Wp + (size_t)(vs_w + mt * 16 + lm) * 32 + quad * 8);

    int sub = lane >> 5, vl = lane & 31;
    int rem = V_CNT - vs_w;
    int nfl = rem >= 32 ? 96 : rem * 3;
    int nh2 = nfl >> 1;

#pragma unroll 1
    for (int t = 0; t < 16; t++) {
        int na = n_w + 2 * t;
        s16x8 ga = *(const s16x8*)(G2 + (size_t)na * 512 + lane * 8);
        s16x8 gb = *(const s16x8*)(G2 + (size_t)(na + 1) * 512 + lane * 8);
        f32x4 ta[2], tb[2];
#pragma unroll
        for (int mt = 0; mt < 2; mt++) {
            ta[mt] = __builtin_amdgcn_mfma_f32_16x16x32_bf16(wf[mt], ga, (f32x4)0.f, 0, 0, 0);
            tb[mt] = __builtin_amdgcn_mfma_f32_16x16x32_bf16(wf[mt], gb, (f32x4)0.f, 0, 0, 0);
        }
#pragma unroll
        for (int mt = 0; mt < 2; mt++)
#pragma unroll
            for (int i = 0; i < 4; i++) {
                Tl[w][0][mt * 16 + quad * 4 + i][lm] = ta[mt][i];
                Tl[w][1][mt * 16 + quad * 4 + i][lm] = tb[mt][i];
            }
        // apply: lane (sub, vl) -> vertex vl of n = na+sub
        const float* Tr = &Tl[w][sub][vl][0];
        const ushort_t* pr0 = &vp[w][vl * 3 + 0][2 * t + sub];
        const ushort_t* pr1 = &vp[w][vl * 3 + 1][2 * t + sub];
        const ushort_t* pr2 = &vp[w][vl * 3 + 2][2 * t + sub];
        float p0 = bf2f(*pr0), p1 = bf2f(*pr1), p2 = bf2f(*pr2);
        float o0 = Tr[3]  + Tr[0] * p0 + Tr[1] * p1 + Tr[2]  * p2;
        float o1 = Tr[7]  + Tr[4] * p0 + Tr[5] * p1 + Tr[6]  * p2;
        float o2 = Tr[11] + Tr[8] * p0 + Tr[9] * p1 + Tr[10] * p2;
        ost[w][sub][vl * 3 + 0] = o0;
        ost[w][sub][vl * 3 + 1] = o1;
        ost[w][sub][vl * 3 + 2] = o2;
#pragma unroll
        for (int s2 = 0; s2 < 2; s2++) {
            float* ob = out + ((size_t)(na + s2) * V_CNT + vs_w) * 3;
            if (lane < nh2)
                *(f32x2*)(ob + lane * 2) = *(const f32x2*)&ost[w][s2][lane * 2];
        }
    }
}

extern "C" void kernel_launch(void* const* d_in, const int* in_sizes, int n_in,
                              void* d_out, int out_size, void* d_ws, size_t ws_size,
                              hipStream_t stream) {
    const float* beta  = (const float*)d_in[0];
    const float* pose  = (const float*)d_in[1];
    const float* vtemp = (const float*)d_in[2];
    const float* sdirs = (const float*)d_in[3];
    const float* pdirs = (const float*)d_in[4];
    const float* jreg  = (const float*)d_in[5];
    const float* wts   = (const float*)d_in[6];
    char* ws = (char*)d_ws;
    float*    ws_part = (float*)(ws + O_PART);
    ushort_t* ws_G2   = (ushort_t*)(ws + O_G2);
    ushort_t* ws_A    = (ushort_t*)(ws + O_A);
    ushort_t* ws_W    = (ushort_t*)(ws + O_W);
    ushort_t* ws_B    = (ushort_t*)(ws + O_B);
    float* out = (float*)d_out;

    k_pre<<<dim3(PREP_BLKS + JS1_BLKS + W_BLKS), dim3(256), 0, stream>>>(
        pdirs, sdirs, vtemp, jreg, wts, ws_B, ws_part, ws_W);
    k_chain<<<dim3(N_B / 2), dim3(128), 0, stream>>>(beta, pose, ws_part, ws_G2, ws_A);
    k_fused<<<dim3(108, N_B / 64), dim3(256), 0, stream>>>(ws_A, ws_B, ws_W, ws_G2, vtemp, out);
}